// Round 7
// baseline (61.038 us; speedup 1.0000x reference)
//
#include <hip/hip_runtime.h>

typedef float  f32x4  __attribute__((ext_vector_type(4)));
typedef float  f32x16 __attribute__((ext_vector_type(16)));
typedef short  s16x8  __attribute__((ext_vector_type(8)));
typedef unsigned int u32;
typedef unsigned short u16;

#define B_N   8
#define C_N   128
#define HW_N  4096
#define G_N   16
#define K_N   2048
#define O_N   256
#define BN    128

__device__ __forceinline__ u16 bf16_bits(float f) {
  u32 u = __builtin_bit_cast(u32, f);
  u32 lsb = (u >> 16) & 1u;
  u += 0x7fffu + lsb;               // round-to-nearest-even
  return (u16)(u >> 16);
}

// ---- prep: W2 f32 [256][2048] -> bf16 32x32x16-fragment-tiled in ws ----
// frag f = (g*8 + mtile)*8 + ks   (g: group, mtile: 32-row tile, ks: k16 step)
// within frag: lane l holds o = mtile*32 + (l&31), k = g*128+ks*16+(l>>5)*8+j
// stored at w2t[f*1024 + l*16], j*2 within the 16B. 1 KB-contiguous frags ->
// one coalesced global_load_dwordx4 per fragment in the main kernel.
__global__ void w2cvt_k(const float* __restrict__ W2, char* __restrict__ w2t) {
  int gid = blockIdx.x * 256 + threadIdx.x;   // 65536 = 1024 frags x 64 lanes
  int f = gid >> 6, l = gid & 63;
  int ks    = f & 7;
  int mtile = (f >> 3) & 7;
  int g     = f >> 6;
  int o = mtile * 32 + (l & 31);
  int k = g * 128 + ks * 16 + (l >> 5) * 8;
  const f32x4* src = reinterpret_cast<const f32x4*>(W2 + (size_t)o * K_N + k);
  f32x4 v0 = src[0], v1 = src[1];
  s16x8 p;
  p[0]=bf16_bits(v0[0]); p[1]=bf16_bits(v0[1]); p[2]=bf16_bits(v0[2]); p[3]=bf16_bits(v0[3]);
  p[4]=bf16_bits(v1[0]); p[5]=bf16_bits(v1[1]); p[6]=bf16_bits(v1[2]); p[7]=bf16_bits(v1[3]);
  *reinterpret_cast<s16x8*>(w2t + (size_t)gid * 16) = p;
}

// ---- main fused kernel ----
// out[o,p] = b2[o] + sum_g fm[g,p] * sum_c W2[o,g*128+c] * x[c,p]
// Block: 128 o x 128 px, 4 waves (2 wm x 2 wn), wave tile 64 x 64.
// 32x32x16 MFMA. B-fragments cached in regs for ALL groups; A direct from
// global (L2-hot, fragment-linear). Main loop: zero barriers, zero LDS ops.
// LDS 40 KB -> 2 blocks/CU: inter-block TLP decorrelates stalls (m114).
__launch_bounds__(256, 2)
__global__ void ccattn_main_k(const float* __restrict__ x,
                              const float* __restrict__ W1,
                              const float* __restrict__ b1,
                              const char* __restrict__ w2t,
                              const float* __restrict__ b2,
                              float* __restrict__ out) {
  __shared__ u16   xT[BN * C_N];       // 32 KB, [px][c] bf16, XOR-swizzled
  __shared__ float fmT[G_N][BN];       // 8 KB

  const int tid = threadIdx.x;
  const int bid = blockIdx.x;
  const int mt  = bid & 1;             // output-channel half
  const int pt  = bid >> 1;
  const int b   = pt >> 5;
  const int px0 = (pt & 31) * BN;

  const float* xb = x + (size_t)b * C_N * HW_N + px0;

  // ---- staging: xT (bf16 [px][c], swizzled, b128 writes) + fm ----
  {
    const int px    = tid & 127;
    const int chalf = tid >> 7;        // channels [0,64) or [64,128)
#pragma unroll
    for (int gg = 0; gg < 8; ++gg) {
      const int g  = chalf * 8 + gg;
      const int c0 = g * 8;
      float v[8];
#pragma unroll
      for (int j = 0; j < 8; ++j) v[j] = xb[(size_t)(c0 + j) * HW_N + px];
      float s = b1[g];
#pragma unroll
      for (int j = 0; j < 8; ++j) s += v[j] * W1[g * 8 + j];
      fmT[g][px] = fmaxf(s, 0.0f);
      s16x8 p;
#pragma unroll
      for (int j = 0; j < 8; ++j) p[j] = (short)bf16_bits(v[j]);
      int byte = (px * 256 + c0 * 2) ^ ((px & 15) << 4);
      *reinterpret_cast<s16x8*>(reinterpret_cast<char*>(xT) + byte) = p;
    }
  }
  __syncthreads();

  // ---- wave decomposition ----
  const int w  = tid >> 6;
  const int l  = tid & 63;
  const int wm = w & 1;                // o offset 0/64
  const int wn = w >> 1;               // px offset 0/64
  const int lw = l & 31;
  const int lh = l >> 5;

  // ---- B-fragment register cache [ks][nf] (valid for every group) ----
  // 32x32x16 B: col px = nf-base + (l&31), k-elems = ks*16 + (l>>5)*8 + j
  s16x8 bfr[8][2];
#pragma unroll
  for (int ks = 0; ks < 8; ++ks)
#pragma unroll
    for (int nf = 0; nf < 2; ++nf) {
      int px   = wn * 64 + nf * 32 + lw;
      int byte = (px * 256 + (ks * 16 + lh * 8) * 2) ^ ((px & 15) << 4);
      bfr[ks][nf] = *reinterpret_cast<const s16x8*>(
          reinterpret_cast<const char*>(xT) + byte);
    }

  f32x16 acc[2][2];
  const f32x16 Z = {0.f};
#pragma unroll
  for (int mf = 0; mf < 2; ++mf)
#pragma unroll
    for (int nf = 0; nf < 2; ++nf) acc[mf][nf] = Z;

  // A base: frag f = (g*8 + mtile)*8 + ks, mtile = mt*4 + wm*2 + mf
  const char* abase = w2t + ((size_t)(mt * 4 + wm * 2) * 8) * 1024 + l * 16;
  // strides: g -> 65536 B, mf -> 8192 B, ks -> 1024 B

  // ---- main loop over 16 groups: pure global-load + MFMA, no barriers ----
  for (int g = 0; g < 16; ++g) {
    const char* ag = abase + (size_t)g * 65536;
    float sn0 = fmT[g][wn * 64 + lw];
    float sn1 = fmT[g][wn * 64 + 32 + lw];

    f32x16 P[2][2];
#pragma unroll
    for (int ks = 0; ks < 8; ++ks) {
      s16x8 a0 = *reinterpret_cast<const s16x8*>(ag + ks * 1024);
      s16x8 a1 = *reinterpret_cast<const s16x8*>(ag + 8192 + ks * 1024);
      P[0][0] = __builtin_amdgcn_mfma_f32_32x32x16_bf16(
          a0, bfr[ks][0], ks == 0 ? Z : P[0][0], 0, 0, 0);
      P[0][1] = __builtin_amdgcn_mfma_f32_32x32x16_bf16(
          a0, bfr[ks][1], ks == 0 ? Z : P[0][1], 0, 0, 0);
      P[1][0] = __builtin_amdgcn_mfma_f32_32x32x16_bf16(
          a1, bfr[ks][0], ks == 0 ? Z : P[1][0], 0, 0, 0);
      P[1][1] = __builtin_amdgcn_mfma_f32_32x32x16_bf16(
          a1, bfr[ks][1], ks == 0 ? Z : P[1][1], 0, 0, 0);
    }
    // fold group into acc: acc += fm[g,px] * P  (VALU pipe, overlaps MFMA)
#pragma unroll
    for (int mf = 0; mf < 2; ++mf)
#pragma unroll
      for (int r = 0; r < 16; ++r) {
        acc[mf][0][r] += sn0 * P[mf][0][r];
        acc[mf][1][r] += sn1 * P[mf][1][r];
      }
  }

  // ---- epilogue: bias + store ----
  // 32x32 C/D: col = lane&31, row = (r&3) + 8*(r>>2) + 4*(lane>>5)
  float* outb = out + (size_t)b * O_N * HW_N + px0;
#pragma unroll
  for (int mf = 0; mf < 2; ++mf)
#pragma unroll
    for (int r = 0; r < 16; ++r) {
      int row = (r & 3) + 8 * (r >> 2) + 4 * lh;
      int o   = mt * 128 + wm * 64 + mf * 32 + row;
      float bias = b2[o];
#pragma unroll
      for (int nf = 0; nf < 2; ++nf) {
        int px = wn * 64 + nf * 32 + lw;
        outb[(size_t)o * HW_N + px] = acc[mf][nf][r] + bias;
      }
    }
}

extern "C" void kernel_launch(void* const* d_in, const int* in_sizes, int n_in,
                              void* d_out, int out_size, void* d_ws, size_t ws_size,
                              hipStream_t stream) {
  const float* x  = (const float*)d_in[0];
  const float* W1 = (const float*)d_in[1];
  const float* b1 = (const float*)d_in[2];
  const float* W2 = (const float*)d_in[3];
  const float* b2 = (const float*)d_in[4];
  float* out = (float*)d_out;
  char* w2t = (char*)d_ws;             // 1 MB fragment-tiled bf16 copy of W2

  w2cvt_k<<<256, 256, 0, stream>>>(W2, w2t);
  ccattn_main_k<<<512, 256, 0, stream>>>(x, W1, b1, w2t, b2, out);
}

// Round 8
// 51.986 us; speedup vs baseline: 1.1741x; 1.1741x over previous
//
#include <hip/hip_runtime.h>

typedef float    f32x4 __attribute__((ext_vector_type(4)));
typedef short    s16x8 __attribute__((ext_vector_type(8)));
typedef _Float16 f16x8 __attribute__((ext_vector_type(8)));
typedef unsigned int u32;
typedef unsigned short u16;

#define B_N   8
#define C_N   128
#define HW_N  4096
#define G_N   16
#define K_N   2048
#define O_N   256
#define BM    128
#define BN    128

// ---- prep: W2 f32 [256][2048] -> fp16 fragment-tiled in ws ----
// layout: byte = (mtile*256 + kc)*256 + (m&15)*16, mtile=m>>4, kc=k>>3.
// For each (16-row tile, 8-col chunk): 16 lanes x 16B contiguous -> the main
// kernel's A-fragment load is one coalesced global_load_dwordx4 per frag.
__global__ void w2cvt_k(const float* __restrict__ W2, char* __restrict__ w2t) {
  int t = blockIdx.x * 256 + threadIdx.x;   // 65536 threads
  int w = t >> 6, l = t & 63;
  int mtile = w >> 6;                       // 0..15
  int kc    = (w & 63) * 4 + (l >> 4);      // 0..255
  int m     = mtile * 16 + (l & 15);
  const f32x4* src = reinterpret_cast<const f32x4*>(W2 + (size_t)m * K_N + kc * 8);
  f32x4 v0 = src[0], v1 = src[1];
  f16x8 p;
  p[0]=(_Float16)v0[0]; p[1]=(_Float16)v0[1]; p[2]=(_Float16)v0[2]; p[3]=(_Float16)v0[3];
  p[4]=(_Float16)v1[0]; p[5]=(_Float16)v1[1]; p[6]=(_Float16)v1[2]; p[7]=(_Float16)v1[3];
  *reinterpret_cast<f16x8*>(w2t + ((size_t)(mtile * 256 + kc) * 256 + (m & 15) * 16)) = p;
}

// ---- main fused kernel ----
// out[o,p] = b2[o] + sum_g fm[g,p] * sum_c W2[o,g*128+c] * x[c,p]
// Block: 128 o x 128 px, 4 waves (2 wm x 2 wn), wave tile 64x64, fp16 MFMA.
// fm folded into the B-operand per group via v_pk_mul_f16 -> MFMA accumulates
// DIRECTLY into acc (no P, 64 AGPRs freed for deep A prefetch).
// Zero barriers / zero LDS ops in the main loop; 2 blocks/CU (m114 TLP).
__launch_bounds__(256, 2)
__global__ void ccattn_main_k(const float* __restrict__ x,
                              const float* __restrict__ W1,
                              const float* __restrict__ b1,
                              const char* __restrict__ w2t,
                              const float* __restrict__ b2,
                              float* __restrict__ out) {
  __shared__ u16   xT[BN * C_N];       // 32 KB, [px][c] fp16, XOR-swizzled
  __shared__ float fmT[G_N][BN];       // 8 KB

  const int tid = threadIdx.x;
  const int bid = blockIdx.x;
  const int mt  = bid & 1;             // output-channel half
  const int pt  = bid >> 1;
  const int b   = pt >> 5;
  const int px0 = (pt & 31) * BN;

  const float* xb = x + (size_t)b * C_N * HW_N + px0;

  // ---- staging: xT (fp16 [px][c], swizzled, b128 writes) + fm (f32) ----
  {
    const int px    = tid & 127;
    const int chalf = tid >> 7;        // channels [0,64) or [64,128)
#pragma unroll
    for (int gg = 0; gg < 8; ++gg) {
      const int g  = chalf * 8 + gg;
      const int c0 = g * 8;
      float v[8];
#pragma unroll
      for (int j = 0; j < 8; ++j) v[j] = xb[(size_t)(c0 + j) * HW_N + px];
      float s = b1[g];
#pragma unroll
      for (int j = 0; j < 8; ++j) s += v[j] * W1[g * 8 + j];
      fmT[g][px] = fmaxf(s, 0.0f);
      f16x8 p;
#pragma unroll
      for (int j = 0; j < 8; ++j) p[j] = (_Float16)v[j];
      int byte = (px * 256 + c0 * 2) ^ ((px & 15) << 4);
      *reinterpret_cast<f16x8*>(reinterpret_cast<char*>(xT) + byte) = p;
    }
  }
  __syncthreads();

  // ---- wave decomposition ----
  const int w  = tid >> 6;
  const int l  = tid & 63;
  const int wm = w & 1;
  const int wn = w >> 1;
  const int lc = l & 15;
  const int lk = l >> 4;

  // ---- B-fragment register cache [ks][nf] (valid for every group) ----
  f16x8 bfr[4][4];
#pragma unroll
  for (int ks = 0; ks < 4; ++ks)
#pragma unroll
    for (int nf = 0; nf < 4; ++nf) {
      int px  = wn * 64 + nf * 16 + lc;
      int byte = (px * 256 + (ks * 32 + lk * 8) * 2) ^ ((px & 15) << 4);
      bfr[ks][nf] = *reinterpret_cast<const f16x8*>(
          reinterpret_cast<const char*>(xT) + byte);
    }

  f32x4 acc[4][4];
  const f32x4 Z = {0.f, 0.f, 0.f, 0.f};
#pragma unroll
  for (int mf = 0; mf < 4; ++mf)
#pragma unroll
    for (int nf = 0; nf < 4; ++nf) acc[mf][nf] = Z;

  // per-mf A base: w2t byte = mtile*65536 + g*4096 + ks*1024 + lk*256 + lc*16
  const char* abase[4];
#pragma unroll
  for (int mf = 0; mf < 4; ++mf)
    abase[mf] = w2t + (size_t)(mt * 8 + wm * 4 + mf) * 65536 + lk * 256 + lc * 16;

  // ---- main loop over 16 groups: loads + pk_mul + MFMA, no barriers ----
  for (int g = 0; g < 16; ++g) {
    // per-nf fm scale, splat to packed f16
    f16x8 sn[4];
#pragma unroll
    for (int nf = 0; nf < 4; ++nf) {
      _Float16 h = (_Float16)fmT[g][wn * 64 + nf * 16 + lc];
      sn[nf] = (f16x8){h, h, h, h, h, h, h, h};
    }
#pragma unroll
    for (int ks = 0; ks < 4; ++ks) {
      f16x8 afr[4];
#pragma unroll
      for (int mf = 0; mf < 4; ++mf)
        afr[mf] = *reinterpret_cast<const f16x8*>(abase[mf] + g * 4096 + ks * 1024);
      f16x8 bs[4];
#pragma unroll
      for (int nf = 0; nf < 4; ++nf) bs[nf] = bfr[ks][nf] * sn[nf];
#pragma unroll
      for (int mf = 0; mf < 4; ++mf)
#pragma unroll
        for (int nf = 0; nf < 4; ++nf)
          acc[mf][nf] = __builtin_amdgcn_mfma_f32_16x16x32_f16(
              afr[mf], bs[nf], acc[mf][nf], 0, 0, 0);
    }
  }

  // ---- epilogue: bias + store ----
  float* outb = out + (size_t)b * O_N * HW_N + px0;
#pragma unroll
  for (int mf = 0; mf < 4; ++mf) {
    int o0 = mt * BM + wm * 64 + mf * 16 + lk * 4;
#pragma unroll
    for (int i = 0; i < 4; ++i) {
      float bias = b2[o0 + i];
#pragma unroll
      for (int nf = 0; nf < 4; ++nf) {
        int px = wn * 64 + nf * 16 + lc;
        outb[(size_t)(o0 + i) * HW_N + px] = acc[mf][nf][i] + bias;
      }
    }
  }
}

extern "C" void kernel_launch(void* const* d_in, const int* in_sizes, int n_in,
                              void* d_out, int out_size, void* d_ws, size_t ws_size,
                              hipStream_t stream) {
  const float* x  = (const float*)d_in[0];
  const float* W1 = (const float*)d_in[1];
  const float* b1 = (const float*)d_in[2];
  const float* W2 = (const float*)d_in[3];
  const float* b2 = (const float*)d_in[4];
  float* out = (float*)d_out;
  char* w2t = (char*)d_ws;             // 1 MB fragment-tiled fp16 copy of W2

  w2cvt_k<<<256, 256, 0, stream>>>(W2, w2t);
  ccattn_main_k<<<512, 256, 0, stream>>>(x, W1, b1, w2t, b2, out);
}

// Round 9
// 46.194 us; speedup vs baseline: 1.3214x; 1.1254x over previous
//
#include <hip/hip_runtime.h>

typedef float    f32x4 __attribute__((ext_vector_type(4)));
typedef _Float16 f16x8 __attribute__((ext_vector_type(8)));
typedef unsigned int u32;
typedef unsigned short u16;

#define B_N   8
#define C_N   128
#define HW_N  4096
#define G_N   16
#define K_N   2048
#define O_N   256
#define BN    64

// ---- prep: W2 f32 [256][2048] -> fp16 fragment-tiled in ws ----
// layout: byte = (mtile*256 + kc)*256 + (m&15)*16, mtile=m>>4, kc=k>>3.
// For each (16-row tile, 8-col chunk): 16 lanes x 16B contiguous -> the main
// kernel's A-fragment load is one coalesced global_load_dwordx4 per frag.
__global__ void w2cvt_k(const float* __restrict__ W2, char* __restrict__ w2t) {
  int t = blockIdx.x * 256 + threadIdx.x;   // 65536 threads
  int w = t >> 6, l = t & 63;
  int mtile = w >> 6;                       // 0..15
  int kc    = (w & 63) * 4 + (l >> 4);      // 0..255
  int m     = mtile * 16 + (l & 15);
  const f32x4* src = reinterpret_cast<const f32x4*>(W2 + (size_t)m * K_N + kc * 8);
  f32x4 v0 = src[0], v1 = src[1];
  f16x8 p;
  p[0]=(_Float16)v0[0]; p[1]=(_Float16)v0[1]; p[2]=(_Float16)v0[2]; p[3]=(_Float16)v0[3];
  p[4]=(_Float16)v1[0]; p[5]=(_Float16)v1[1]; p[6]=(_Float16)v1[2]; p[7]=(_Float16)v1[3];
  *reinterpret_cast<f16x8*>(w2t + ((size_t)(mtile * 256 + kc) * 256 + (m & 15) * 16)) = p;
}

// ---- main fused kernel ----
// out[o,p] = b2[o] + sum_g fm[g,p] * sum_c W2[o,g*128+c] * x[c,p]
// Block: 128 o x 64 px, 4 waves, wave tile 32 o x 64 px (no A-dup in block).
// fp16 MFMA, fm folded into B via v_pk_mul_f16 (no P accumulator: 32 AGPR).
// Zero barriers / zero LDS-A. Small block -> grid 1024 -> 3 blocks/CU,
// 3 waves/SIMD: TLP hides the A-load path (m114 mechanism).
__launch_bounds__(256, 3)
__global__ void ccattn_main_k(const float* __restrict__ x,
                              const float* __restrict__ W1,
                              const float* __restrict__ b1,
                              const char* __restrict__ w2t,
                              const float* __restrict__ b2,
                              float* __restrict__ out) {
  __shared__ u16   xT[BN * C_N];       // 16 KB, [px][c] fp16, XOR-swizzled
  __shared__ float fmT[G_N][BN];       // 4 KB

  const int tid = threadIdx.x;
  const int bid = blockIdx.x;
  const int mt  = bid & 1;             // output-channel half
  const int pt  = bid >> 1;            // 512 px-tiles
  const int b   = pt >> 6;             // batch
  const int px0 = (pt & 63) * BN;

  const float* xb = x + (size_t)b * C_N * HW_N + px0;

  // ---- staging: xT (fp16 [px][c], swizzled, b128 writes) + fm (f32) ----
  {
    const int px = tid & 63;
    const int cq = tid >> 6;           // 4 groups each
#pragma unroll
    for (int gg = 0; gg < 4; ++gg) {
      const int g  = cq * 4 + gg;
      const int c0 = g * 8;
      float v[8];
#pragma unroll
      for (int j = 0; j < 8; ++j) v[j] = xb[(size_t)(c0 + j) * HW_N + px];
      float s = b1[g];
#pragma unroll
      for (int j = 0; j < 8; ++j) s += v[j] * W1[g * 8 + j];
      fmT[g][px] = fmaxf(s, 0.0f);
      f16x8 p;
#pragma unroll
      for (int j = 0; j < 8; ++j) p[j] = (_Float16)v[j];
      int byte = (px * 256 + c0 * 2) ^ ((px & 15) << 4);
      *reinterpret_cast<f16x8*>(reinterpret_cast<char*>(xT) + byte) = p;
    }
  }
  __syncthreads();

  // ---- wave decomposition: wave w owns o-rows [w*32, w*32+32) ----
  const int w  = tid >> 6;
  const int l  = tid & 63;
  const int lc = l & 15;
  const int lk = l >> 4;

  // ---- B-fragment register cache [ks][nf] (valid for every group) ----
  f16x8 bfr[4][4];
#pragma unroll
  for (int ks = 0; ks < 4; ++ks)
#pragma unroll
    for (int nf = 0; nf < 4; ++nf) {
      int px  = nf * 16 + lc;
      int byte = (px * 256 + (ks * 32 + lk * 8) * 2) ^ ((px & 15) << 4);
      bfr[ks][nf] = *reinterpret_cast<const f16x8*>(
          reinterpret_cast<const char*>(xT) + byte);
    }

  f32x4 acc[2][4];
  const f32x4 Z = {0.f, 0.f, 0.f, 0.f};
#pragma unroll
  for (int mf = 0; mf < 2; ++mf)
#pragma unroll
    for (int nf = 0; nf < 4; ++nf) acc[mf][nf] = Z;

  // per-mf A base: w2t byte = mtile*65536 + g*4096 + ks*1024 + lk*256 + lc*16
  const char* abase0 = w2t + (size_t)(mt * 8 + w * 2 + 0) * 65536 + lk * 256 + lc * 16;
  const char* abase1 = w2t + (size_t)(mt * 8 + w * 2 + 1) * 65536 + lk * 256 + lc * 16;

  // ---- main loop over 16 groups: loads + pk_mul + MFMA, no barriers ----
  for (int g = 0; g < 16; ++g) {
    f16x8 sn[4];
#pragma unroll
    for (int nf = 0; nf < 4; ++nf) {
      _Float16 h = (_Float16)fmT[g][nf * 16 + lc];
      sn[nf] = (f16x8){h, h, h, h, h, h, h, h};
    }
#pragma unroll
    for (int ks = 0; ks < 4; ++ks) {
      f16x8 a0 = *reinterpret_cast<const f16x8*>(abase0 + g * 4096 + ks * 1024);
      f16x8 a1 = *reinterpret_cast<const f16x8*>(abase1 + g * 4096 + ks * 1024);
      f16x8 bs[4];
#pragma unroll
      for (int nf = 0; nf < 4; ++nf) bs[nf] = bfr[ks][nf] * sn[nf];
#pragma unroll
      for (int nf = 0; nf < 4; ++nf) {
        acc[0][nf] = __builtin_amdgcn_mfma_f32_16x16x32_f16(a0, bs[nf], acc[0][nf], 0, 0, 0);
        acc[1][nf] = __builtin_amdgcn_mfma_f32_16x16x32_f16(a1, bs[nf], acc[1][nf], 0, 0, 0);
      }
    }
  }

  // ---- epilogue: bias + store ----
  float* outb = out + (size_t)b * O_N * HW_N + px0;
#pragma unroll
  for (int mf = 0; mf < 2; ++mf) {
    int o0 = mt * 128 + w * 32 + mf * 16 + lk * 4;
#pragma unroll
    for (int i = 0; i < 4; ++i) {
      float bias = b2[o0 + i];
#pragma unroll
      for (int nf = 0; nf < 4; ++nf) {
        int px = nf * 16 + lc;
        outb[(size_t)(o0 + i) * HW_N + px] = acc[mf][nf][i] + bias;
      }
    }
  }
}

extern "C" void kernel_launch(void* const* d_in, const int* in_sizes, int n_in,
                              void* d_out, int out_size, void* d_ws, size_t ws_size,
                              hipStream_t stream) {
  const float* x  = (const float*)d_in[0];
  const float* W1 = (const float*)d_in[1];
  const float* b1 = (const float*)d_in[2];
  const float* W2 = (const float*)d_in[3];
  const float* b2 = (const float*)d_in[4];
  float* out = (float*)d_out;
  char* w2t = (char*)d_ws;             // 1 MB fragment-tiled fp16 copy of W2

  w2cvt_k<<<256, 256, 0, stream>>>(W2, w2t);
  ccattn_main_k<<<1024, 256, 0, stream>>>(x, W1, b1, w2t, b2, out);
}

// Round 10
// 44.441 us; speedup vs baseline: 1.3735x; 1.0394x over previous
//
#include <hip/hip_runtime.h>

typedef float    f32x4 __attribute__((ext_vector_type(4)));
typedef _Float16 f16x8 __attribute__((ext_vector_type(8)));
typedef unsigned int u32;
typedef unsigned short u16;

#define B_N   8
#define C_N   128
#define HW_N  4096
#define G_N   16
#define K_N   2048
#define O_N   256
#define BN    64

// ---- prep: W2 f32 [256][2048] -> fp16 fragment-tiled in ws ----
// layout: byte = (mtile*256 + kc)*256 + (m&15)*16, mtile=m>>4, kc=k>>3.
// For each (16-row tile, 8-col chunk): 16 lanes x 16B contiguous -> the main
// kernel's A-fragment load is one coalesced global_load_dwordx4 per frag.
__global__ void w2cvt_k(const float* __restrict__ W2, char* __restrict__ w2t) {
  int t = blockIdx.x * 256 + threadIdx.x;   // 65536 threads
  int w = t >> 6, l = t & 63;
  int mtile = w >> 6;                       // 0..15
  int kc    = (w & 63) * 4 + (l >> 4);      // 0..255
  int m     = mtile * 16 + (l & 15);
  const f32x4* src = reinterpret_cast<const f32x4*>(W2 + (size_t)m * K_N + kc * 8);
  f32x4 v0 = src[0], v1 = src[1];
  f16x8 p;
  p[0]=(_Float16)v0[0]; p[1]=(_Float16)v0[1]; p[2]=(_Float16)v0[2]; p[3]=(_Float16)v0[3];
  p[4]=(_Float16)v1[0]; p[5]=(_Float16)v1[1]; p[6]=(_Float16)v1[2]; p[7]=(_Float16)v1[3];
  *reinterpret_cast<f16x8*>(w2t + ((size_t)(mtile * 256 + kc) * 256 + (m & 15) * 16)) = p;
}

// ---- main fused kernel ----
// out[o,p] = b2[o] + sum_g fm[g,p] * sum_c W2[o,g*128+c] * x[c,p]
// Block: 128 o x 64 px, 4 waves, wave tile 32 o x 64 px.  fp16 MFMA,
// fm folded into B via v_pk_mul_f16 (no P accumulator: 32 AGPR).
// A-stream EXPLICITLY double-buffered in registers (pA/pB half-group
// buffers, prefetch distance = 16 MFMA > L2 latency). Zero barriers.
__launch_bounds__(256, 3)
__global__ void ccattn_main_k(const float* __restrict__ x,
                              const float* __restrict__ W1,
                              const float* __restrict__ b1,
                              const char* __restrict__ w2t,
                              const float* __restrict__ b2,
                              float* __restrict__ out) {
  __shared__ u16   xT[BN * C_N];       // 16 KB, [px][c] fp16, XOR-swizzled
  __shared__ float fmT[G_N][BN];       // 4 KB

  const int tid = threadIdx.x;
  const int bid = blockIdx.x;
  const int mt  = bid & 1;             // output-channel half
  const int pt  = bid >> 1;            // 512 px-tiles
  const int b   = pt >> 6;             // batch
  const int px0 = (pt & 63) * BN;

  const float* xb = x + (size_t)b * C_N * HW_N + px0;

  // ---- staging: xT (fp16 [px][c], swizzled, b128 writes) + fm (f32) ----
  {
    const int px = tid & 63;
    const int cq = tid >> 6;           // 4 groups each
#pragma unroll
    for (int gg = 0; gg < 4; ++gg) {
      const int g  = cq * 4 + gg;
      const int c0 = g * 8;
      float v[8];
#pragma unroll
      for (int j = 0; j < 8; ++j) v[j] = xb[(size_t)(c0 + j) * HW_N + px];
      float s = b1[g];
#pragma unroll
      for (int j = 0; j < 8; ++j) s += v[j] * W1[g * 8 + j];
      fmT[g][px] = fmaxf(s, 0.0f);
      f16x8 p;
#pragma unroll
      for (int j = 0; j < 8; ++j) p[j] = (_Float16)v[j];
      int byte = (px * 256 + c0 * 2) ^ ((px & 15) << 4);
      *reinterpret_cast<f16x8*>(reinterpret_cast<char*>(xT) + byte) = p;
    }
  }
  __syncthreads();

  // ---- wave decomposition: wave w owns o-rows [w*32, w*32+32) ----
  const int w  = tid >> 6;
  const int l  = tid & 63;
  const int lc = l & 15;
  const int lk = l >> 4;

  // ---- B-fragment register cache [ks][nf] (valid for every group) ----
  f16x8 bfr[4][4];
#pragma unroll
  for (int ks = 0; ks < 4; ++ks)
#pragma unroll
    for (int nf = 0; nf < 4; ++nf) {
      int px  = nf * 16 + lc;
      int byte = (px * 256 + (ks * 32 + lk * 8) * 2) ^ ((px & 15) << 4);
      bfr[ks][nf] = *reinterpret_cast<const f16x8*>(
          reinterpret_cast<const char*>(xT) + byte);
    }

  f32x4 acc[2][4];
  const f32x4 Z = {0.f, 0.f, 0.f, 0.f};
#pragma unroll
  for (int mf = 0; mf < 2; ++mf)
#pragma unroll
    for (int nf = 0; nf < 4; ++nf) acc[mf][nf] = Z;

  // A bases: byte = mtile*65536 + g*4096 + ks*1024 + lk*256 + lc*16
  const char* ab0 = w2t + (size_t)(mt * 8 + w * 2 + 0) * 65536 + lk * 256 + lc * 16;
  const char* ab1 = w2t + (size_t)(mt * 8 + w * 2 + 1) * 65536 + lk * 256 + lc * 16;

  // half-group A buffers: p[0]=mt0@ksA, p[1]=mt1@ksA, p[2]=mt0@ksB, p[3]=mt1@ksB
  f16x8 pA[4], pB[4];
#define LDH(dst, g, half)                                                  \
  {                                                                        \
    const char* _b0 = ab0 + (g) * 4096 + (half) * 2048;                    \
    const char* _b1 = ab1 + (g) * 4096 + (half) * 2048;                    \
    dst[0] = *reinterpret_cast<const f16x8*>(_b0);                         \
    dst[1] = *reinterpret_cast<const f16x8*>(_b1);                         \
    dst[2] = *reinterpret_cast<const f16x8*>(_b0 + 1024);                  \
    dst[3] = *reinterpret_cast<const f16x8*>(_b1 + 1024);                  \
  }
  LDH(pA, 0, 0)
  LDH(pB, 0, 1)

  float snC[4], snN[4];
#pragma unroll
  for (int nf = 0; nf < 4; ++nf) {
    snC[nf] = fmT[0][nf * 16 + lc];
    snN[nf] = fmT[1][nf * 16 + lc];
  }

  // ---- main loop: 16 groups, register-double-buffered A, no barriers ----
#pragma unroll 1
  for (int g = 0; g < 16; ++g) {
    f16x8 s8[4];
#pragma unroll
    for (int nf = 0; nf < 4; ++nf) {
      _Float16 h = (_Float16)snC[nf];
      s8[nf] = (f16x8){h, h, h, h, h, h, h, h};
    }
    const int gn = (g < 15) ? g + 1 : 15;   // clamped dup-load is harmless

    // half 0 (ks 0,1) from pA
#pragma unroll
    for (int nf = 0; nf < 4; ++nf) {
      f16x8 bs = bfr[0][nf] * s8[nf];
      acc[0][nf] = __builtin_amdgcn_mfma_f32_16x16x32_f16(pA[0], bs, acc[0][nf], 0, 0, 0);
      acc[1][nf] = __builtin_amdgcn_mfma_f32_16x16x32_f16(pA[1], bs, acc[1][nf], 0, 0, 0);
    }
#pragma unroll
    for (int nf = 0; nf < 4; ++nf) {
      f16x8 bs = bfr[1][nf] * s8[nf];
      acc[0][nf] = __builtin_amdgcn_mfma_f32_16x16x32_f16(pA[2], bs, acc[0][nf], 0, 0, 0);
      acc[1][nf] = __builtin_amdgcn_mfma_f32_16x16x32_f16(pA[3], bs, acc[1][nf], 0, 0, 0);
    }
    LDH(pA, gn, 0)                       // prefetch next group's half 0

    // half 1 (ks 2,3) from pB
#pragma unroll
    for (int nf = 0; nf < 4; ++nf) {
      f16x8 bs = bfr[2][nf] * s8[nf];
      acc[0][nf] = __builtin_amdgcn_mfma_f32_16x16x32_f16(pB[0], bs, acc[0][nf], 0, 0, 0);
      acc[1][nf] = __builtin_amdgcn_mfma_f32_16x16x32_f16(pB[1], bs, acc[1][nf], 0, 0, 0);
    }
#pragma unroll
    for (int nf = 0; nf < 4; ++nf) {
      f16x8 bs = bfr[3][nf] * s8[nf];
      acc[0][nf] = __builtin_amdgcn_mfma_f32_16x16x32_f16(pB[2], bs, acc[0][nf], 0, 0, 0);
      acc[1][nf] = __builtin_amdgcn_mfma_f32_16x16x32_f16(pB[3], bs, acc[1][nf], 0, 0, 0);
    }
    LDH(pB, gn, 1)                       // prefetch next group's half 1

    // rotate fm lookahead
    const int g2 = (g < 14) ? g + 2 : 15;
#pragma unroll
    for (int nf = 0; nf < 4; ++nf) {
      snC[nf] = snN[nf];
      snN[nf] = fmT[g2][nf * 16 + lc];
    }
  }
#undef LDH

  // ---- epilogue: bias + store ----
  float* outb = out + (size_t)b * O_N * HW_N + px0;
#pragma unroll
  for (int mf = 0; mf < 2; ++mf) {
    int o0 = mt * 128 + w * 32 + mf * 16 + lk * 4;
#pragma unroll
    for (int i = 0; i < 4; ++i) {
      float bias = b2[o0 + i];
#pragma unroll
      for (int nf = 0; nf < 4; ++nf) {
        int px = nf * 16 + lc;
        outb[(size_t)(o0 + i) * HW_N + px] = acc[mf][nf][i] + bias;
      }
    }
  }
}

extern "C" void kernel_launch(void* const* d_in, const int* in_sizes, int n_in,
                              void* d_out, int out_size, void* d_ws, size_t ws_size,
                              hipStream_t stream) {
  const float* x  = (const float*)d_in[0];
  const float* W1 = (const float*)d_in[1];
  const float* b1 = (const float*)d_in[2];
  const float* W2 = (const float*)d_in[3];
  const float* b2 = (const float*)d_in[4];
  float* out = (float*)d_out;
  char* w2t = (char*)d_ws;             // 1 MB fragment-tiled fp16 copy of W2

  w2cvt_k<<<256, 256, 0, stream>>>(W2, w2t);
  ccattn_main_k<<<1024, 256, 0, stream>>>(x, W1, b1, w2t, b2, out);
}